// Round 13
// baseline (99.115 us; speedup 1.0000x reference)
//
#include <hip/hip_runtime.h>
#include <hip/hip_bf16.h>
#include <cstdint>

#define BATCH  2
#define SEQ    2048
#define DMODEL 1024
#define NH     16
#define DH     64

typedef short bf16x8 __attribute__((ext_vector_type(8)));
typedef float f32x4  __attribute__((ext_vector_type(4)));
typedef unsigned short u16;

#define MFMA16(a, b, c) __builtin_amdgcn_mfma_f32_16x16x32_bf16((a), (b), (c), 0, 0, 0)

#define GLL(gp, lp) __builtin_amdgcn_global_load_lds( \
    (const __attribute__((address_space(1))) void*)(gp), \
    (__attribute__((address_space(3))) void*)(lp), 16, 0, 0)

// score scale 1/sqrt(64) folded with log2(e); baked into Wq at transpose time
#define SCL 0.18033688011112042f

#if __has_builtin(__builtin_amdgcn_exp2f)
#define EXP2(x) __builtin_amdgcn_exp2f(x)
#else
#define EXP2(x) __expf((x) * 0.69314718055994531f)
#endif

static __device__ __forceinline__ u16 f2bf(float f) {
  union { float f; unsigned int i; } u; u.f = f;
  unsigned int r = u.i + 0x7FFFu + ((u.i >> 16) & 1u);  // round-nearest-even
  return (u16)(r >> 16);
}

// ---------------- x fp32 -> bf16 ----------------
__global__ __launch_bounds__(256) void convert_x_kernel(const float* __restrict__ X,
                                                        u16* __restrict__ Xb) {
  int idx = (blockIdx.x * 256 + threadIdx.x) * 8;
  float4 a = *reinterpret_cast<const float4*>(X + idx);
  float4 b = *reinterpret_cast<const float4*>(X + idx + 4);
  union { bf16x8 v; u16 u[8]; } pk;
  pk.u[0]=f2bf(a.x); pk.u[1]=f2bf(a.y); pk.u[2]=f2bf(a.z); pk.u[3]=f2bf(a.w);
  pk.u[4]=f2bf(b.x); pk.u[5]=f2bf(b.y); pk.u[6]=f2bf(b.z); pk.u[7]=f2bf(b.w);
  *reinterpret_cast<bf16x8*>(Xb + idx) = pk.v;
}

// ---------------- W [k][n] fp32 -> Wt [n][k] bf16 (Wq scaled by SCL) ----------------
__global__ __launch_bounds__(256) void transpose_w_kernel(const float* __restrict__ W0,
                                                          const float* __restrict__ W1,
                                                          const float* __restrict__ W2,
                                                          u16* __restrict__ Wt) {
  const float* W = (blockIdx.z == 0) ? W0 : (blockIdx.z == 1) ? W1 : W2;
  const float sc = (blockIdx.z == 0) ? SCL : 1.0f;
  u16* out = Wt + (size_t)blockIdx.z * DMODEL * DMODEL;
  __shared__ float T[32][33];
  const int t = threadIdx.x;
  const int k0 = blockIdx.x * 32, n0 = blockIdx.y * 32;
  {
    int r = t >> 3, c = (t & 7) * 4;
    float4 v = *reinterpret_cast<const float4*>(W + (size_t)(k0 + r) * DMODEL + n0 + c);
    T[r][c] = v.x; T[r][c+1] = v.y; T[r][c+2] = v.z; T[r][c+3] = v.w;
  }
  __syncthreads();
  {
    int n = t >> 3, k = (t & 7) * 4;
    union { unsigned long long ll; u16 u[4]; } pk;
    pk.u[0] = f2bf(T[k][n] * sc);   pk.u[1] = f2bf(T[k+1][n] * sc);
    pk.u[2] = f2bf(T[k+2][n] * sc); pk.u[3] = f2bf(T[k+3][n] * sc);
    *reinterpret_cast<unsigned long long*>(out + (size_t)(n0 + n) * DMODEL + k0 + k) = pk.ll;
  }
}

// ---------------- QKV GEMM: Y[b,h,s,dh](bf16) = Xb[bs][k] * Wt[n][k]^T ----------
__global__ __launch_bounds__(256) void qkv_mfma_kernel(const u16* __restrict__ Xb,
                                                       const u16* __restrict__ Wt,
                                                       u16* __restrict__ Y) {
  __shared__ u16 As[128 * 64];
  __shared__ u16 Bs[128 * 64];
  char* Ab = (char*)As; char* Bb = (char*)Bs;
  const int t = threadIdx.x;
  const int lane = t & 63;
  const int w = t >> 6;
  const int wr = w >> 1, wc = w & 1;
  const int l15 = lane & 15, lg = lane >> 4;
  const int row0 = blockIdx.x * 128;
  const int col0 = blockIdx.y * 128;
  const int z = blockIdx.z;
  const u16* Wz = Wt + (size_t)z * DMODEL * DMODEL;
  u16* Yz = Y + (size_t)z * ((size_t)BATCH * SEQ * DMODEL);

  f32x4 acc[4][4];
  #pragma unroll
  for (int mt = 0; mt < 4; ++mt)
    #pragma unroll
    for (int nt = 0; nt < 4; ++nt)
      acc[mt][nt] = (f32x4){0.f, 0.f, 0.f, 0.f};

  size_t aofs[4], bofs[4];
  #pragma unroll
  for (int it = 0; it < 4; ++it) {
    int row = it * 32 + (t >> 3);
    int sl  = (t & 7) ^ (row & 7);
    aofs[it] = (size_t)(row0 + row) * DMODEL + sl * 8;
    bofs[it] = (size_t)(col0 + row) * DMODEL + sl * 8;
  }

  for (int k0 = 0; k0 < DMODEL; k0 += 64) {
    __syncthreads();
    #pragma unroll
    for (int it = 0; it < 4; ++it) {
      GLL(Xb + aofs[it] + k0, Ab + it * 4096 + w * 1024);
      GLL(Wz + bofs[it] + k0, Bb + it * 4096 + w * 1024);
    }
    __syncthreads();
    #pragma unroll
    for (int c = 0; c < 2; ++c) {
      bf16x8 am[4], bn[4];
      int kof = c * 64 + lg * 16;
      #pragma unroll
      for (int mt = 0; mt < 4; ++mt) {
        int row = wr * 64 + mt * 16 + l15;
        am[mt] = *reinterpret_cast<const bf16x8*>(Ab + row * 128 + (kof ^ ((row & 7) << 4)));
      }
      #pragma unroll
      for (int nt = 0; nt < 4; ++nt) {
        int row = wc * 64 + nt * 16 + l15;
        bn[nt] = *reinterpret_cast<const bf16x8*>(Bb + row * 128 + (kof ^ ((row & 7) << 4)));
      }
      #pragma unroll
      for (int mt = 0; mt < 4; ++mt)
        #pragma unroll
        for (int nt = 0; nt < 4; ++nt)
          acc[mt][nt] = MFMA16(am[mt], bn[nt], acc[mt][nt]);
    }
  }

  #pragma unroll
  for (int mt = 0; mt < 4; ++mt) {
    #pragma unroll
    for (int i = 0; i < 4; ++i) {
      int bs = row0 + wr * 64 + mt * 16 + lg * 4 + i;
      int b = bs >> 11, s = bs & (SEQ - 1);
      #pragma unroll
      for (int nt = 0; nt < 4; ++nt) {
        int d = col0 + wc * 64 + nt * 16 + l15;
        int h = d >> 6, dd = d & (DH - 1);
        size_t off = (((size_t)b * NH + h) * SEQ + s) * DH + dd;
        Yz[off] = f2bf(acc[mt][nt][i]);
      }
    }
  }
}

// ---------------- V [b,h,s,dh] -> Vt [b,h,dh,s] ----------------
__global__ __launch_bounds__(256) void transpose_v_kernel(const u16* __restrict__ V,
                                                          u16* __restrict__ Vt) {
  __shared__ u16 L[64][72];
  const int sb = blockIdx.x, h = blockIdx.y, b = blockIdx.z;
  const size_t hin  = ((size_t)b * NH + h) * (size_t)SEQ * DH;
  const size_t hout = ((size_t)b * NH + h) * (size_t)DH * SEQ;
  const int s0 = sb * 64;
  const int t = threadIdx.x;
  const int r = t >> 3, c = t & 7;
  #pragma unroll
  for (int it = 0; it < 2; ++it) {
    int row = r + it * 32;
    bf16x8 v = *reinterpret_cast<const bf16x8*>(V + hin + (size_t)(s0 + row) * DH + c * 8);
    *reinterpret_cast<bf16x8*>(&L[row][c * 8]) = v;
  }
  __syncthreads();
  #pragma unroll
  for (int it = 0; it < 2; ++it) {
    int d = r + it * 32;
    union { bf16x8 v; u16 u[8]; } pk;
    #pragma unroll
    for (int j = 0; j < 8; ++j) pk.u[j] = L[c * 8 + j][d];
    *reinterpret_cast<bf16x8*>(Vt + hout + (size_t)d * SEQ + s0 + c * 8) = pk.v;
  }
}

// stage K and V 64-key tile (kb) into the wave's single LDS buffers (16 GLL)
#define STAGE(kb)                                                     \
  {                                                                   \
    const u16* kp_ = Kw + hq + (size_t)(kb) * (64 * DH);              \
    const u16* vp_ = Vt + hv + (size_t)(kb) * 64;                     \
    _Pragma("unroll")                                                 \
    for (int it = 0; it < 8; ++it) {                                  \
      GLL(kp_ + kofs[it], (char*)Ksb + it * 1024);                    \
      GLL(vp_ + vofs[it], (char*)Vsb + it * 1024);                    \
    }                                                                 \
  }

#define WAITV()                                                       \
  asm volatile("s_waitcnt vmcnt(0)" ::: "memory");                    \
  __builtin_amdgcn_sched_barrier(0)

// one 64-key tile: swapped QK^T for two q-halves, no-max exp2 softmax, PV.
// MASKED is a compile-time 0/1 at each expansion site.
#define TILE(kbv, MASKED)                                                            \
  {                                                                                  \
    char* Kb = (char*)Ksb;                                                           \
    char* Vb = (char*)Vsb;                                                           \
    const int k0_ = (kbv) * 64;                                                      \
    __builtin_amdgcn_s_setprio(1);                                                   \
    _Pragma("unroll")                                                                \
    for (int kt = 0; kt < 4; ++kt) {                                                 \
      bf16x8 kf0 = *reinterpret_cast<const bf16x8*>(Kb + kvb0 + kt * 2048);          \
      bf16x8 kf1 = *reinterpret_cast<const bf16x8*>(Kb + kvb1 + kt * 2048);          \
      f32x4 sA = (f32x4){0.f, 0.f, 0.f, 0.f};                                        \
      f32x4 sB = (f32x4){0.f, 0.f, 0.f, 0.f};                                        \
      sA = MFMA16(kf0, qfA0, sA); sA = MFMA16(kf1, qfA1, sA);                        \
      sB = MFMA16(kf0, qfB0, sB); sB = MFMA16(kf1, qfB1, sB);                        \
      union { unsigned long long ll; __hip_bfloat16 bf[4]; } pA, pB;                 \
      _Pragma("unroll")                                                              \
      for (int i = 0; i < 4; ++i) {                                                  \
        float svA = sA[i], svB = sB[i];                                              \
        if (MASKED) {                                                                \
          int key = k0_ + kt * 16 + lg * 4 + i;                                      \
          if (key > qrowA) svA = -1e30f;                                             \
          if (key > qrowB) svB = -1e30f;                                             \
        }                                                                            \
        float eA = EXP2(svA), eB = EXP2(svB);                                        \
        l_A += eA; l_B += eB;                                                        \
        pA.bf[i] = __float2bfloat16(eA);                                             \
        pB.bf[i] = __float2bfloat16(eB);                                             \
      }                                                                              \
      int kx = (kt * 32) ^ xw;                                                       \
      *reinterpret_cast<unsigned long long*>(PbW + pwA + kx) = pA.ll;                \
      *reinterpret_cast<unsigned long long*>(PbW + pwB + kx) = pB.ll;                \
    }                                                                                \
    _Pragma("unroll")                                                                \
    for (int kc = 0; kc < 2; ++kc) {                                                 \
      const int tg = kc * 64;                                                        \
      bf16x8 paA = *reinterpret_cast<const bf16x8*>(PbW + (kvb0 ^ tg));              \
      bf16x8 paB = *reinterpret_cast<const bf16x8*>(PbW + (kvb0 ^ tg) + 2048);       \
      _Pragma("unroll")                                                              \
      for (int dt = 0; dt < 4; ++dt) {                                               \
        bf16x8 vv = *reinterpret_cast<const bf16x8*>(Vb + (kvb0 ^ tg) + dt * 2048);  \
        oA[dt] = MFMA16(paA, vv, oA[dt]);                                            \
        oB[dt] = MFMA16(paB, vv, oB[dt]);                                            \
      }                                                                              \
    }                                                                                \
    __builtin_amdgcn_s_setprio(0);                                                   \
  }

// ---------------- Flash attention: 1-wave blocks (32 q-rows), KVBLK=64,
// single-buffer GLL staging, no barriers, 8 blocks/CU, balanced qt mapping ----
__global__ __launch_bounds__(64) void flash_mfma10_kernel(const u16* __restrict__ Qw,
                                                          const u16* __restrict__ Kw,
                                                          const u16* __restrict__ Vt,
                                                          float* __restrict__ Out) {
  __shared__ u16 Ksb[64 * 64];        // key(64) x d(64), chunk-swizzled content (8 KB)
  __shared__ u16 Vsb[64 * 64];        // d(64) x key(64), chunk-swizzled content (8 KB)
  __shared__ u16 Pw[32 * 64];         // P [q(32) x key(64)], swizzled (4 KB)

  const int wgid = blockIdx.x;
  const int g = wgid & 31;            // head-group; XCD pinned: g%8 == wgid%8
  const int j = (wgid >> 5) & 7;
  const int r = wgid >> 8;            // 0..7
  const int qt = r * 8 + ((r & 1) ? (7 - j) : j);   // balanced: CU-mates sum uniform
  const int b = g >> 4, h = g & 15;
  const int nkv = (qt >> 1) + 1;

  const int lane = threadIdx.x;       // 64-thread block = 1 wave
  const int l15 = lane & 15, lg = lane >> 4;
  char* PbW = (char*)Pw;
  const size_t hq = ((size_t)b * NH + h) * (size_t)SEQ * DH;
  const size_t hv = ((size_t)b * NH + h) * (size_t)DH * SEQ;

  // staging: per-lane pre-swizzled source offsets; linear LDS dest
  int kofs[8], vofs[8];
  #pragma unroll
  for (int it = 0; it < 8; ++it) {
    int idx = it * 64 + lane;
    int row = idx >> 3, sl = idx & 7;
    kofs[it] = row * DH  + ((sl ^ (row & 7)) * 8);
    vofs[it] = row * SEQ + ((sl ^ (row & 7)) * 8);
  }

  // affine swizzled read bases (dual-base handles the bit-6 XOR)
  const int kvb0 = l15 * 128 + ((lg * 16) ^ ((l15 & 3) << 4)) + ((l15 & 4) << 4);
  const int kvb1 = kvb0 ^ 64;
  const int pwA  = l15 * 128 + ((lg * 8) ^ ((l15 & 1) << 4));
  const int pwB  = pwA + 2048;
  const int xw   = ((l15 >> 1) & 3) << 5;

  const int qbase = qt * 32;
  const int qrowA = qbase + l15;
  const int qrowB = qbase + 16 + l15;

  // Q fragments (B-operand of swapped QK; Wq pre-scaled -> log2-domain scores)
  bf16x8 qfA0, qfA1, qfB0, qfB1;
  {
    const u16* qpA = Qw + hq + (size_t)qrowA * DH + lg * 8;
    const u16* qpB = Qw + hq + (size_t)qrowB * DH + lg * 8;
    qfA0 = *reinterpret_cast<const bf16x8*>(qpA);
    qfA1 = *reinterpret_cast<const bf16x8*>(qpA + 32);
    qfB0 = *reinterpret_cast<const bf16x8*>(qpB);
    qfB1 = *reinterpret_cast<const bf16x8*>(qpB + 32);
  }

  f32x4 oA[4], oB[4];
  #pragma unroll
  for (int dt = 0; dt < 4; ++dt) {
    oA[dt] = (f32x4){0.f, 0.f, 0.f, 0.f};
    oB[dt] = (f32x4){0.f, 0.f, 0.f, 0.f};
  }
  float l_A = 0.f, l_B = 0.f;

  // full tiles (branch-free; all keys valid)
  #pragma unroll 1
  for (int kb = 0; kb < nkv - 1; ++kb) {
    STAGE(kb);
    WAITV();
    TILE(kb, 0);
  }
  // diagonal tile (mask-select)
  STAGE(nkv - 1);
  WAITV();
  TILE(nkv - 1, 1);

  // epilogue: reduce l across lg groups, redistribute, normalize, store
  l_A += __shfl_xor(l_A, 16); l_A += __shfl_xor(l_A, 32);
  l_B += __shfl_xor(l_B, 16); l_B += __shfl_xor(l_B, 32);
  #pragma unroll
  for (int i = 0; i < 4; ++i) {
    float liA = __shfl(l_A, (lane & 48) + lg * 4 + i);
    float liB = __shfl(l_B, (lane & 48) + lg * 4 + i);
    float invA = 1.f / liA, invB = 1.f / liB;
    int qA = qbase + lg * 4 + i;
    int qB = qbase + 16 + lg * 4 + i;
    float* opA = Out + ((size_t)b * SEQ + qA) * DMODEL + h * DH + l15;
    float* opB = Out + ((size_t)b * SEQ + qB) * DMODEL + h * DH + l15;
    #pragma unroll
    for (int dt = 0; dt < 4; ++dt) {
      opA[dt * 16] = oA[dt][i] * invA;
      opB[dt * 16] = oB[dt][i] * invB;
    }
  }
}

extern "C" void kernel_launch(void* const* d_in, const int* in_sizes, int n_in,
                              void* d_out, int out_size, void* d_ws, size_t ws_size,
                              hipStream_t stream) {
  const float* x  = (const float*)d_in[0];
  const float* Wq = (const float*)d_in[1];
  const float* Wk = (const float*)d_in[2];
  const float* Wv = (const float*)d_in[3];
  float* out = (float*)d_out;

  u16* ws  = (u16*)d_ws;
  u16* qkv = ws;                         // 3 x 4,194,304 bf16  (24 MB)
  u16* xb  = ws + 12582912;              // 4,194,304 bf16      ( 8 MB)
  u16* wt  = ws + 16777216;              // 3 x 1,048,576 bf16  ( 6 MB)
  u16* vt  = ws + 19922944;              // 4,194,304 bf16      ( 8 MB)

  convert_x_kernel<<<2048, 256, 0, stream>>>(x, xb);
  transpose_w_kernel<<<dim3(32, 32, 3), 256, 0, stream>>>(Wq, Wk, Wv, wt);
  qkv_mfma_kernel<<<dim3(32, 8, 3), 256, 0, stream>>>(xb, wt, qkv);
  transpose_v_kernel<<<dim3(32, NH, BATCH), 256, 0, stream>>>(qkv + 8388608, vt);
  flash_mfma10_kernel<<<2048, 64, 0, stream>>>(qkv, qkv + 4194304, vt, out);
}

// Round 14
// 93.350 us; speedup vs baseline: 1.0618x; 1.0618x over previous
//
#include <hip/hip_runtime.h>
#include <hip/hip_bf16.h>
#include <cstdint>

#define BATCH  2
#define SEQ    2048
#define DMODEL 1024
#define NH     16
#define DH     64

typedef short bf16x8 __attribute__((ext_vector_type(8)));
typedef float f32x4  __attribute__((ext_vector_type(4)));
typedef unsigned short u16;

#define MFMA16(a, b, c) __builtin_amdgcn_mfma_f32_16x16x32_bf16((a), (b), (c), 0, 0, 0)

#define GLL(gp, lp) __builtin_amdgcn_global_load_lds( \
    (const __attribute__((address_space(1))) void*)(gp), \
    (__attribute__((address_space(3))) void*)(lp), 16, 0, 0)

// score scale 1/sqrt(64) folded with log2(e); baked into Wq at transpose time
#define SCL 0.18033688011112042f

#if __has_builtin(__builtin_amdgcn_exp2f)
#define EXP2(x) __builtin_amdgcn_exp2f(x)
#else
#define EXP2(x) __expf((x) * 0.69314718055994531f)
#endif

static __device__ __forceinline__ u16 f2bf(float f) {
  union { float f; unsigned int i; } u; u.f = f;
  unsigned int r = u.i + 0x7FFFu + ((u.i >> 16) & 1u);  // round-nearest-even
  return (u16)(r >> 16);
}

// ---------------- x fp32 -> bf16 ----------------
__global__ __launch_bounds__(256) void convert_x_kernel(const float* __restrict__ X,
                                                        u16* __restrict__ Xb) {
  int idx = (blockIdx.x * 256 + threadIdx.x) * 8;
  float4 a = *reinterpret_cast<const float4*>(X + idx);
  float4 b = *reinterpret_cast<const float4*>(X + idx + 4);
  union { bf16x8 v; u16 u[8]; } pk;
  pk.u[0]=f2bf(a.x); pk.u[1]=f2bf(a.y); pk.u[2]=f2bf(a.z); pk.u[3]=f2bf(a.w);
  pk.u[4]=f2bf(b.x); pk.u[5]=f2bf(b.y); pk.u[6]=f2bf(b.z); pk.u[7]=f2bf(b.w);
  *reinterpret_cast<bf16x8*>(Xb + idx) = pk.v;
}

// ---------------- W [k][n] fp32 -> Wt [n][k] bf16 (Wq scaled by SCL) ----------------
__global__ __launch_bounds__(256) void transpose_w_kernel(const float* __restrict__ W0,
                                                          const float* __restrict__ W1,
                                                          const float* __restrict__ W2,
                                                          u16* __restrict__ Wt) {
  const float* W = (blockIdx.z == 0) ? W0 : (blockIdx.z == 1) ? W1 : W2;
  const float sc = (blockIdx.z == 0) ? SCL : 1.0f;
  u16* out = Wt + (size_t)blockIdx.z * DMODEL * DMODEL;
  __shared__ float T[32][33];
  const int t = threadIdx.x;
  const int k0 = blockIdx.x * 32, n0 = blockIdx.y * 32;
  {
    int r = t >> 3, c = (t & 7) * 4;
    float4 v = *reinterpret_cast<const float4*>(W + (size_t)(k0 + r) * DMODEL + n0 + c);
    T[r][c] = v.x; T[r][c+1] = v.y; T[r][c+2] = v.z; T[r][c+3] = v.w;
  }
  __syncthreads();
  {
    int n = t >> 3, k = (t & 7) * 4;
    union { unsigned long long ll; u16 u[4]; } pk;
    pk.u[0] = f2bf(T[k][n] * sc);   pk.u[1] = f2bf(T[k+1][n] * sc);
    pk.u[2] = f2bf(T[k+2][n] * sc); pk.u[3] = f2bf(T[k+3][n] * sc);
    *reinterpret_cast<unsigned long long*>(out + (size_t)(n0 + n) * DMODEL + k0 + k) = pk.ll;
  }
}

// ---------------- QKV GEMM: Y[b,h,s,dh](bf16) = Xb[bs][k] * Wt[n][k]^T ----------
__global__ __launch_bounds__(256) void qkv_mfma_kernel(const u16* __restrict__ Xb,
                                                       const u16* __restrict__ Wt,
                                                       u16* __restrict__ Y) {
  __shared__ u16 As[128 * 64];
  __shared__ u16 Bs[128 * 64];
  char* Ab = (char*)As; char* Bb = (char*)Bs;
  const int t = threadIdx.x;
  const int lane = t & 63;
  const int w = t >> 6;
  const int wr = w >> 1, wc = w & 1;
  const int l15 = lane & 15, lg = lane >> 4;
  const int row0 = blockIdx.x * 128;
  const int col0 = blockIdx.y * 128;
  const int z = blockIdx.z;
  const u16* Wz = Wt + (size_t)z * DMODEL * DMODEL;
  u16* Yz = Y + (size_t)z * ((size_t)BATCH * SEQ * DMODEL);

  f32x4 acc[4][4];
  #pragma unroll
  for (int mt = 0; mt < 4; ++mt)
    #pragma unroll
    for (int nt = 0; nt < 4; ++nt)
      acc[mt][nt] = (f32x4){0.f, 0.f, 0.f, 0.f};

  size_t aofs[4], bofs[4];
  #pragma unroll
  for (int it = 0; it < 4; ++it) {
    int row = it * 32 + (t >> 3);
    int sl  = (t & 7) ^ (row & 7);
    aofs[it] = (size_t)(row0 + row) * DMODEL + sl * 8;
    bofs[it] = (size_t)(col0 + row) * DMODEL + sl * 8;
  }

  for (int k0 = 0; k0 < DMODEL; k0 += 64) {
    __syncthreads();
    #pragma unroll
    for (int it = 0; it < 4; ++it) {
      GLL(Xb + aofs[it] + k0, Ab + it * 4096 + w * 1024);
      GLL(Wz + bofs[it] + k0, Bb + it * 4096 + w * 1024);
    }
    __syncthreads();
    #pragma unroll
    for (int c = 0; c < 2; ++c) {
      bf16x8 am[4], bn[4];
      int kof = c * 64 + lg * 16;
      #pragma unroll
      for (int mt = 0; mt < 4; ++mt) {
        int row = wr * 64 + mt * 16 + l15;
        am[mt] = *reinterpret_cast<const bf16x8*>(Ab + row * 128 + (kof ^ ((row & 7) << 4)));
      }
      #pragma unroll
      for (int nt = 0; nt < 4; ++nt) {
        int row = wc * 64 + nt * 16 + l15;
        bn[nt] = *reinterpret_cast<const bf16x8*>(Bb + row * 128 + (kof ^ ((row & 7) << 4)));
      }
      #pragma unroll
      for (int mt = 0; mt < 4; ++mt)
        #pragma unroll
        for (int nt = 0; nt < 4; ++nt)
          acc[mt][nt] = MFMA16(am[mt], bn[nt], acc[mt][nt]);
    }
  }

  #pragma unroll
  for (int mt = 0; mt < 4; ++mt) {
    #pragma unroll
    for (int i = 0; i < 4; ++i) {
      int bs = row0 + wr * 64 + mt * 16 + lg * 4 + i;
      int b = bs >> 11, s = bs & (SEQ - 1);
      #pragma unroll
      for (int nt = 0; nt < 4; ++nt) {
        int d = col0 + wc * 64 + nt * 16 + l15;
        int h = d >> 6, dd = d & (DH - 1);
        size_t off = (((size_t)b * NH + h) * SEQ + s) * DH + dd;
        Yz[off] = f2bf(acc[mt][nt][i]);
      }
    }
  }
}

// ---------------- V [b,h,s,dh] -> Vt [b,h,dh,s] ----------------
__global__ __launch_bounds__(256) void transpose_v_kernel(const u16* __restrict__ V,
                                                          u16* __restrict__ Vt) {
  __shared__ u16 L[64][72];
  const int sb = blockIdx.x, h = blockIdx.y, b = blockIdx.z;
  const size_t hin  = ((size_t)b * NH + h) * (size_t)SEQ * DH;
  const size_t hout = ((size_t)b * NH + h) * (size_t)DH * SEQ;
  const int s0 = sb * 64;
  const int t = threadIdx.x;
  const int r = t >> 3, c = t & 7;
  #pragma unroll
  for (int it = 0; it < 2; ++it) {
    int row = r + it * 32;
    bf16x8 v = *reinterpret_cast<const bf16x8*>(V + hin + (size_t)(s0 + row) * DH + c * 8);
    *reinterpret_cast<bf16x8*>(&L[row][c * 8]) = v;
  }
  __syncthreads();
  #pragma unroll
  for (int it = 0; it < 2; ++it) {
    int d = r + it * 32;
    union { bf16x8 v; u16 u[8]; } pk;
    #pragma unroll
    for (int j = 0; j < 8; ++j) pk.u[j] = L[c * 8 + j][d];
    *reinterpret_cast<bf16x8*>(Vt + hout + (size_t)d * SEQ + s0 + c * 8) = pk.v;
  }
}

// stage K and V 64-key tile (kb) into explicit LDS buffers (16 GLL)
#define STAGE(KD, VD, kb)                                             \
  {                                                                   \
    const u16* kp_ = Kw + hq + (size_t)(kb) * (64 * DH);              \
    const u16* vp_ = Vt + hv + (size_t)(kb) * 64;                     \
    _Pragma("unroll")                                                 \
    for (int it = 0; it < 8; ++it) {                                  \
      GLL(kp_ + kofs[it], (char*)(KD) + it * 1024);                   \
      GLL(vp_ + vofs[it], (char*)(VD) + it * 1024);                   \
    }                                                                 \
  }

// counted vmem wait: allow the newest N loads to stay in flight
#define WAITC(N)                                                      \
  asm volatile("s_waitcnt vmcnt(" #N ")" ::: "memory");               \
  __builtin_amdgcn_sched_barrier(0)

// one 64-key tile: swapped QK^T for two q-halves, no-max exp2 softmax, PV.
#define TILE(kbv, KBUF, VBUF, MASKED)                                                \
  {                                                                                  \
    char* Kb = (char*)(KBUF);                                                        \
    char* Vb = (char*)(VBUF);                                                        \
    const int k0_ = (kbv) * 64;                                                      \
    __builtin_amdgcn_s_setprio(1);                                                   \
    _Pragma("unroll")                                                                \
    for (int kt = 0; kt < 4; ++kt) {                                                 \
      bf16x8 kf0 = *reinterpret_cast<const bf16x8*>(Kb + kvb0 + kt * 2048);          \
      bf16x8 kf1 = *reinterpret_cast<const bf16x8*>(Kb + kvb1 + kt * 2048);          \
      f32x4 sA = (f32x4){0.f, 0.f, 0.f, 0.f};                                        \
      f32x4 sB = (f32x4){0.f, 0.f, 0.f, 0.f};                                        \
      sA = MFMA16(kf0, qfA0, sA); sA = MFMA16(kf1, qfA1, sA);                        \
      sB = MFMA16(kf0, qfB0, sB); sB = MFMA16(kf1, qfB1, sB);                        \
      union { unsigned long long ll; __hip_bfloat16 bf[4]; } pA, pB;                 \
      _Pragma("unroll")                                                              \
      for (int i = 0; i < 4; ++i) {                                                  \
        float svA = sA[i], svB = sB[i];                                              \
        if (MASKED) {                                                                \
          int key = k0_ + kt * 16 + lg * 4 + i;                                      \
          if (key > qrowA) svA = -1e30f;                                             \
          if (key > qrowB) svB = -1e30f;                                             \
        }                                                                            \
        float eA = EXP2(svA), eB = EXP2(svB);                                        \
        l_A += eA; l_B += eB;                                                        \
        pA.bf[i] = __float2bfloat16(eA);                                             \
        pB.bf[i] = __float2bfloat16(eB);                                             \
      }                                                                              \
      int kx = (kt * 32) ^ xw;                                                       \
      *reinterpret_cast<unsigned long long*>(PbW + pwA + kx) = pA.ll;                \
      *reinterpret_cast<unsigned long long*>(PbW + pwB + kx) = pB.ll;                \
    }                                                                                \
    _Pragma("unroll")                                                                \
    for (int kc = 0; kc < 2; ++kc) {                                                 \
      const int tg = kc * 64;                                                        \
      bf16x8 paA = *reinterpret_cast<const bf16x8*>(PbW + (kvb0 ^ tg));              \
      bf16x8 paB = *reinterpret_cast<const bf16x8*>(PbW + (kvb0 ^ tg) + 2048);       \
      _Pragma("unroll")                                                              \
      for (int dt = 0; dt < 4; ++dt) {                                               \
        bf16x8 vv = *reinterpret_cast<const bf16x8*>(Vb + (kvb0 ^ tg) + dt * 2048);  \
        oA[dt] = MFMA16(paA, vv, oA[dt]);                                            \
        oB[dt] = MFMA16(paB, vv, oB[dt]);                                            \
      }                                                                              \
    }                                                                                \
    __builtin_amdgcn_s_setprio(0);                                                   \
  }

// ---------------- Flash attention: 1-wave blocks (32 q-rows), KVBLK=64,
// K/V LDS double-buffer + counted vmcnt(16) pipeline, no barriers,
// LPT-ordered 2048-block grid (2x residency -> refill queue), XCD-pinned heads ----
__global__ __launch_bounds__(64) void flash_mfma11_kernel(const u16* __restrict__ Qw,
                                                          const u16* __restrict__ Kw,
                                                          const u16* __restrict__ Vt,
                                                          float* __restrict__ Out) {
  __shared__ u16 KsA[64 * 64];        // 8 KB each
  __shared__ u16 KsB[64 * 64];
  __shared__ u16 VsA[64 * 64];
  __shared__ u16 VsB[64 * 64];
  __shared__ u16 Pw[32 * 64];         // P [q(32) x key(64)], swizzled (4 KB)

  const int wgid = blockIdx.x;
  const int g = wgid & 31;            // head-group; XCD pinned: g%8 == wgid%8
  const int qt = 63 - (wgid >> 5);    // LPT: longest q-tiles dispatched first
  const int b = g >> 4, h = g & 15;
  const int nkv = (qt >> 1) + 1;

  const int lane = threadIdx.x;       // 64-thread block = 1 wave
  const int l15 = lane & 15, lg = lane >> 4;
  char* PbW = (char*)Pw;
  const size_t hq = ((size_t)b * NH + h) * (size_t)SEQ * DH;
  const size_t hv = ((size_t)b * NH + h) * (size_t)DH * SEQ;

  // staging: per-lane pre-swizzled source offsets; linear LDS dest
  int kofs[8], vofs[8];
  #pragma unroll
  for (int it = 0; it < 8; ++it) {
    int idx = it * 64 + lane;
    int row = idx >> 3, sl = idx & 7;
    kofs[it] = row * DH  + ((sl ^ (row & 7)) * 8);
    vofs[it] = row * SEQ + ((sl ^ (row & 7)) * 8);
  }

  // affine swizzled read bases (dual-base handles the bit-6 XOR)
  const int kvb0 = l15 * 128 + ((lg * 16) ^ ((l15 & 3) << 4)) + ((l15 & 4) << 4);
  const int kvb1 = kvb0 ^ 64;
  const int pwA  = l15 * 128 + ((lg * 8) ^ ((l15 & 1) << 4));
  const int pwB  = pwA + 2048;
  const int xw   = ((l15 >> 1) & 3) << 5;

  const int qbase = qt * 32;
  const int qrowA = qbase + l15;
  const int qrowB = qbase + 16 + l15;

  // Q fragments (B-operand of swapped QK; Wq pre-scaled -> log2-domain scores)
  bf16x8 qfA0, qfA1, qfB0, qfB1;
  {
    const u16* qpA = Qw + hq + (size_t)qrowA * DH + lg * 8;
    const u16* qpB = Qw + hq + (size_t)qrowB * DH + lg * 8;
    qfA0 = *reinterpret_cast<const bf16x8*>(qpA);
    qfA1 = *reinterpret_cast<const bf16x8*>(qpA + 32);
    qfB0 = *reinterpret_cast<const bf16x8*>(qpB);
    qfB1 = *reinterpret_cast<const bf16x8*>(qpB + 32);
  }

  f32x4 oA[4], oB[4];
  #pragma unroll
  for (int dt = 0; dt < 4; ++dt) {
    oA[dt] = (f32x4){0.f, 0.f, 0.f, 0.f};
    oB[dt] = (f32x4){0.f, 0.f, 0.f, 0.f};
  }
  float l_A = 0.f, l_B = 0.f;

  // software pipeline: stage t+1 into the other buffer, wait only for tile t's
  // 16 loads (vmcnt(16) leaves t+1's in flight), compute tile t.
  STAGE(KsA, VsA, 0);
  int kb = 0;
  #pragma unroll 1
  while (kb + 2 < nkv) {
    STAGE(KsB, VsB, kb + 1);
    WAITC(16);
    TILE(kb, KsA, VsA, 0);
    STAGE(KsA, VsA, kb + 2);
    WAITC(16);
    TILE(kb + 1, KsB, VsB, 0);
    kb += 2;
  }
  if (kb + 2 == nkv) {                // two tiles left: full, then diagonal
    STAGE(KsB, VsB, kb + 1);
    WAITC(16);
    TILE(kb, KsA, VsA, 0);
    WAITC(0);
    TILE(kb + 1, KsB, VsB, 1);
  } else {                            // one tile left: diagonal
    WAITC(0);
    TILE(kb, KsA, VsA, 1);
  }

  // epilogue: reduce l across lg groups, redistribute, normalize, store
  l_A += __shfl_xor(l_A, 16); l_A += __shfl_xor(l_A, 32);
  l_B += __shfl_xor(l_B, 16); l_B += __shfl_xor(l_B, 32);
  #pragma unroll
  for (int i = 0; i < 4; ++i) {
    float liA = __shfl(l_A, (lane & 48) + lg * 4 + i);
    float liB = __shfl(l_B, (lane & 48) + lg * 4 + i);
    float invA = 1.f / liA, invB = 1.f / liB;
    int qA = qbase + lg * 4 + i;
    int qB = qbase + 16 + lg * 4 + i;
    float* opA = Out + ((size_t)b * SEQ + qA) * DMODEL + h * DH + l15;
    float* opB = Out + ((size_t)b * SEQ + qB) * DMODEL + h * DH + l15;
    #pragma unroll
    for (int dt = 0; dt < 4; ++dt) {
      opA[dt * 16] = oA[dt][i] * invA;
      opB[dt * 16] = oB[dt][i] * invB;
    }
  }
}

extern "C" void kernel_launch(void* const* d_in, const int* in_sizes, int n_in,
                              void* d_out, int out_size, void* d_ws, size_t ws_size,
                              hipStream_t stream) {
  const float* x  = (const float*)d_in[0];
  const float* Wq = (const float*)d_in[1];
  const float* Wk = (const float*)d_in[2];
  const float* Wv = (const float*)d_in[3];
  float* out = (float*)d_out;

  u16* ws  = (u16*)d_ws;
  u16* qkv = ws;                         // 3 x 4,194,304 bf16  (24 MB)
  u16* xb  = ws + 12582912;              // 4,194,304 bf16      ( 8 MB)
  u16* wt  = ws + 16777216;              // 3 x 1,048,576 bf16  ( 6 MB)
  u16* vt  = ws + 19922944;              // 4,194,304 bf16      ( 8 MB)

  convert_x_kernel<<<2048, 256, 0, stream>>>(x, xb);
  transpose_w_kernel<<<dim3(32, 32, 3), 256, 0, stream>>>(Wq, Wk, Wv, wt);
  qkv_mfma_kernel<<<dim3(32, 8, 3), 256, 0, stream>>>(xb, wt, qkv);
  transpose_v_kernel<<<dim3(32, NH, BATCH), 256, 0, stream>>>(qkv + 8388608, vt);
  flash_mfma11_kernel<<<2048, 64, 0, stream>>>(qkv, qkv + 4194304, vt, out);
}